// Round 13
// baseline (239.321 us; speedup 1.0000x reference)
//
#include <hip/hip_runtime.h>

constexpr int B = 8, N = 8192, S = 2048, D = 64, K = 16, C = 3 + D;
constexpr int G = 4;  // queries per block

// Map float -> monotonically sortable unsigned (total order matches float <)
__device__ __forceinline__ unsigned sortable(float f) {
    unsigned u = __float_as_uint(f);
    unsigned mask = (unsigned)(((int)u) >> 31) | 0x80000000u;
    return u ^ mask;
}

// Wave-uniform load -> SGPR
__device__ __forceinline__ float uload(const float* p) {
    return __uint_as_float(__builtin_amdgcn_readfirstlane(__float_as_uint(*p)));
}

// Scalar reference-exact distance (fallback path): dot asc-FMA, d=(pn-2dot)+qn [R8]
__device__ __forceinline__ float make_d(float px, float py, float pz, float pnv,
                                        float qx, float qy, float qz, float qn) {
    float dot = __fmaf_rn(pz, qz, __fmaf_rn(py, qy, __fmul_rn(px, qx)));
    return __fadd_rn(__fsub_rn(pnv, __fmul_rn(2.0f, dot)), qn);
}

// v = pn - dot2 where dot2 = fma(pz,q2z, fma(py,q2y, px*q2x)) == 2*dot bitwise
__device__ __forceinline__ float make_v(float px, float py, float pz, float pnv,
                                        float q2x, float q2y, float q2z) {
    float dot2 = __fmaf_rn(pz, q2z, __fmaf_rn(py, q2y, __fmul_rn(px, q2x)));
    return __fsub_rn(pnv, dot2);
}

__device__ __forceinline__ float bitonic_sort64_f32(float v, int lane) {
#pragma unroll
    for (int k = 2; k <= 64; k <<= 1)
#pragma unroll
        for (int j = k >> 1; j > 0; j >>= 1) {
            float o = __shfl_xor(v, j, 64);
            bool keepmin = ((lane & k) == 0) == ((lane & j) == 0);
            float mn = fminf(v, o), mx = fmaxf(v, o);
            v = keepmin ? mn : mx;
        }
    return v;
}

__device__ __forceinline__ unsigned long long bitonic_sort64_u64(unsigned long long v, int lane) {
#pragma unroll
    for (int k = 2; k <= 64; k <<= 1)
#pragma unroll
        for (int j = k >> 1; j > 0; j >>= 1) {
            unsigned long long o = __shfl_xor(v, j, 64);
            bool keepmin = ((lane & k) == 0) == ((lane & j) == 0);
            v = ((v < o) == keepmin) ? v : o;
        }
    return v;
}

// pts4[b][n] = {x, y, z, ||p||^2}; norm = (z*z + y*y) + x*x desc no-FMA [verified R8]
__global__ void pack_kernel(const float* __restrict__ pts, float4* __restrict__ pts4) {
    int t = blockIdx.x * blockDim.x + threadIdx.x;
    if (t >= B * N) return;
    int b = t >> 13, n = t & (N - 1);
    const float* P = pts + (size_t)b * 3 * N;
    float x = P[n], y = P[N + n], z = P[2 * N + n];
    float pn = __fadd_rn(__fadd_rn(__fmul_rn(z, z), __fmul_rn(y, y)), __fmul_rn(x, x));
    pts4[t] = make_float4(x, y, z, pn);
}

// feat [B][D][N] -> featT [B][N][D], LDS-tiled 64x64
__global__ void __launch_bounds__(256) transpose_kernel(const float* __restrict__ feat,
                                                        float* __restrict__ featT) {
    __shared__ float tile[64][65];
    int b = blockIdx.x >> 7;
    int n0 = (blockIdx.x & 127) << 6;
    int col = threadIdx.x & 63;
    int crow = threadIdx.x >> 6;
    const float* F = feat + (size_t)b * D * N;
#pragma unroll
    for (int i = 0; i < 16; ++i) {
        int c = i * 4 + crow;
        tile[c][col] = F[(size_t)c * N + n0 + col];
    }
    __syncthreads();
    float* FT = featT + ((size_t)b * N + n0) * D;
#pragma unroll
    for (int i = 0; i < 16; ++i) {
        int nl = i * 4 + crow;
        FT[(size_t)nl * D + col] = tile[col][nl];
    }
}

// Block-cooperative: 4 waves per block, one block per G=4 queries; wave w scans
// candidate chunk [w*N/4, (w+1)*N/4). Pass 1: per-wave tau_w (16th lane-min of
// v over chunk) -> LDS -> tau_v = min_w tau_w (valid bound since chunk-16th >=
// global-16th and rn is monotone). Pass 2: pre-filter v <= vthr, exact d check,
// block-shared LDS-atomic compact. Wave g sorts query g's 64 keys and emits 16.
__global__ void __launch_bounds__(256) knn_kernel(const float4* __restrict__ pts4,
                                                  const float* __restrict__ newp,
                                                  int* __restrict__ ind) {
    __shared__ unsigned long long buf[G][64];
    __shared__ float tauw[4][G];
    __shared__ int cnt_lds[G];
    int wib = threadIdx.x >> 6;
    int lane = threadIdx.x & 63;
    int bid = blockIdx.x;
    int b = bid >> 9;              // S/G = 512 blocks per batch
    int sbase = (bid & 511) * G;
    const float4* P4 = pts4 + (size_t)b * N;
    const float* Q = newp + (size_t)b * 3 * S;
    if (threadIdx.x < G) cnt_lds[threadIdx.x] = 0;
    float qn[G], q2x[G], q2y[G], q2z[G];
#pragma unroll
    for (int g = 0; g < G; ++g) {
        int s = sbase + g;
        float qx = uload(Q + s), qy = uload(Q + S + s), qz = uload(Q + 2 * S + s);
        qn[g] = __fadd_rn(__fadd_rn(__fmul_rn(qz, qz), __fmul_rn(qy, qy)), __fmul_rn(qx, qx));
        q2x[g] = 2.0f * qx;  // exact pow-2 scale
        q2y[g] = 2.0f * qy;
        q2z[g] = 2.0f * qz;
    }
    int chunk0 = wib * (N / 4);  // this wave's 2048-candidate chunk

    // ---- pass 1: per-lane min of v over chunk ----
    float m[G];
#pragma unroll
    for (int g = 0; g < G; ++g) m[g] = __int_as_float(0x7f800000);
    for (int blk = 0; blk < N / 4 / 256; ++blk) {
        int nb = chunk0 + blk * 256 + lane;
        float4 c0 = P4[nb], c1 = P4[nb + 64], c2 = P4[nb + 128], c3 = P4[nb + 192];
#pragma unroll
        for (int g = 0; g < G; ++g) {
            float v0 = make_v(c0.x, c0.y, c0.z, c0.w, q2x[g], q2y[g], q2z[g]);
            float v1 = make_v(c1.x, c1.y, c1.z, c1.w, q2x[g], q2y[g], q2z[g]);
            float v2 = make_v(c2.x, c2.y, c2.z, c2.w, q2x[g], q2y[g], q2z[g]);
            float v3 = make_v(c3.x, c3.y, c3.z, c3.w, q2x[g], q2y[g], q2z[g]);
            m[g] = fminf(m[g], fminf(fminf(v0, v1), fminf(v2, v3)));
        }
    }
#pragma unroll
    for (int g = 0; g < G; ++g) {
        float tw = __shfl(bitonic_sort64_f32(m[g], lane), 15, 64);
        if (lane == 0) tauw[wib][g] = tw;
    }
    __syncthreads();
    float tau_d[G], vthr[G];
#pragma unroll
    for (int g = 0; g < G; ++g) {
        float tv = fminf(fminf(tauw[0][g], tauw[1][g]), fminf(tauw[2][g], tauw[3][g]));
        tau_d[g] = __fadd_rn(tv, qn[g]);  // >= 16th-smallest distance (proof in header)
        vthr[g] = __fadd_rn(__fsub_rn(tau_d[g], qn[g]), 1e-4f);  // superset pre-filter
    }

    // ---- pass 2: pre-filter on v, exact check + block LDS-atomic compact ----
    for (int blk = 0; blk < N / 4 / 256; ++blk) {
        int nb = chunk0 + blk * 256 + lane;
        float4 c0 = P4[nb], c1 = P4[nb + 64], c2 = P4[nb + 128], c3 = P4[nb + 192];
#pragma unroll
        for (int g = 0; g < G; ++g) {
            float vv[4];
            vv[0] = make_v(c0.x, c0.y, c0.z, c0.w, q2x[g], q2y[g], q2z[g]);
            vv[1] = make_v(c1.x, c1.y, c1.z, c1.w, q2x[g], q2y[g], q2z[g]);
            vv[2] = make_v(c2.x, c2.y, c2.z, c2.w, q2x[g], q2y[g], q2z[g]);
            vv[3] = make_v(c3.x, c3.y, c3.z, c3.w, q2x[g], q2y[g], q2z[g]);
#pragma unroll
            for (int i = 0; i < 4; ++i) {
                if (vv[i] <= vthr[g]) {  // rare divergent branch
                    float d = __fadd_rn(vv[i], qn[g]);  // exact reference d
                    if (d <= tau_d[g]) {
                        int pos = atomicAdd(&cnt_lds[g], 1);
                        if (pos < 64)
                            buf[g][pos] =
                                ((unsigned long long)sortable(d) << 32) | (unsigned)(nb + i * 64);
                    }
                }
            }
        }
    }
    __syncthreads();

    // ---- final: wave wib owns query g = wib ----
    {
        int g = wib;
        int cnt = cnt_lds[g];
        int* my_ind = ind + ((size_t)b * S + sbase + g) * K;
        if (cnt <= 64) {
            unsigned long long key = (lane < cnt) ? buf[g][lane] : ~0ull;
            key = bitonic_sort64_u64(key, lane);
            if (lane < K) my_ind[lane] = (int)(unsigned)key;
        } else {
            // Exact fallback (never expected): this wave rescans ALL of N.
            float qx = 0.5f * q2x[g], qy = 0.5f * q2y[g], qz = 0.5f * q2z[g];
            unsigned long long a[K];
#pragma unroll
            for (int i = 0; i < K; ++i) a[i] = ~0ull;
            for (int n = lane; n < N; n += 64) {
                float4 c = P4[n];
                float d = make_d(c.x, c.y, c.z, c.w, qx, qy, qz, qn[g]);
                unsigned long long key = ((unsigned long long)sortable(d) << 32) | (unsigned)n;
                if (key < a[K - 1]) {
#pragma unroll
                    for (int i = K - 1; i >= 1; --i) {
                        unsigned long long lo = a[i - 1];
                        a[i] = key < lo ? lo : (key < a[i] ? key : a[i]);
                    }
                    a[0] = key < a[0] ? key : a[0];
                }
            }
            for (int r = 0; r < K; ++r) {
                unsigned long long best = a[0];
#pragma unroll
                for (int mm = 1; mm < 64; mm <<= 1) {
                    unsigned long long o = __shfl_xor(best, mm, 64);
                    best = o < best ? o : best;
                }
                if (lane == 0) my_ind[r] = (int)(unsigned)best;
                bool won = (a[0] == best);
#pragma unroll
                for (int i = 0; i < K - 1; ++i) a[i] = won ? a[i + 1] : a[i];
                a[K - 1] = won ? ~0ull : a[K - 1];
            }
        }
    }
}

// Output [B][C][K][S]. t -> (b, g, k, s); g=0: 3 coord channels from pts4;
// g=1..16: 4 feat channels via one float4 from featT (or 4 scalar loads).
__global__ void __launch_bounds__(256) gather_kernel(const float4* __restrict__ pts4,
                                                     const float* __restrict__ newp,
                                                     const float* __restrict__ feat,
                                                     const float* __restrict__ featT,
                                                     const int* __restrict__ ind,
                                                     float* __restrict__ out, int useT) {
    int t = blockIdx.x * blockDim.x + threadIdx.x;
    int s = t & (S - 1);
    int k = (t >> 11) & (K - 1);
    int rest = t >> 15;
    int g = rest % 17;
    int b = rest / 17;
    if (b >= B) return;
    int id = ind[((size_t)b * S + s) * K + k];
    size_t KS = (size_t)K * S;
    if (g == 0) {
        float4 p = pts4[(size_t)b * N + id];
        const float* Q = newp + (size_t)b * 3 * S;
        float* o = out + ((size_t)b * C * K + k) * S + s;
        o[0] = __fsub_rn(p.x, Q[s]);
        o[KS] = __fsub_rn(p.y, Q[S + s]);
        o[2 * KS] = __fsub_rn(p.z, Q[2 * S + s]);
    } else {
        int cb = (g - 1) * 4;
        float4 f;
        if (useT) {
            f = *(const float4*)(featT + ((size_t)b * N + id) * D + cb);
        } else {
            const float* F = feat + (size_t)b * D * N;
            f = make_float4(F[(size_t)cb * N + id], F[(size_t)(cb + 1) * N + id],
                            F[(size_t)(cb + 2) * N + id], F[(size_t)(cb + 3) * N + id]);
        }
        float* o = out + (((size_t)b * C + 3 + cb) * K + k) * S + s;
        o[0] = f.x;
        o[KS] = f.y;
        o[2 * KS] = f.z;
        o[3 * KS] = f.w;
    }
}

extern "C" void kernel_launch(void* const* d_in, const int* in_sizes, int n_in,
                              void* d_out, int out_size, void* d_ws, size_t ws_size,
                              hipStream_t stream) {
    const float* pts = (const float*)d_in[0];   // [B, 3, N]
    const float* newp = (const float*)d_in[1];  // [B, 3, S]
    const float* feat = (const float*)d_in[2];  // [B, D, N]
    float* out = (float*)d_out;                 // [B, C, K, S]

    size_t off_ind = 0;
    size_t off_pts4 = (size_t)B * S * K * sizeof(int);              // 2 MB
    size_t off_featT = off_pts4 + (size_t)B * N * sizeof(float4);   // +1 MB
    size_t need = off_featT + (size_t)B * N * D * sizeof(float);    // +16 MB
    int* ind = (int*)((char*)d_ws + off_ind);
    float4* pts4 = (float4*)((char*)d_ws + off_pts4);
    float* featT = (float*)((char*)d_ws + off_featT);
    int useT = (ws_size >= need) ? 1 : 0;

    pack_kernel<<<(B * N) / 256, 256, 0, stream>>>(pts, pts4);
    if (useT) transpose_kernel<<<B * (N / 64), 256, 0, stream>>>(feat, featT);
    knn_kernel<<<B * S / G, 256, 0, stream>>>(pts4, newp, ind);
    gather_kernel<<<(B * 17 * K * S) / 256, 256, 0, stream>>>(pts4, newp, feat, featT, ind, out, useT);
}

// Round 14
// 131.869 us; speedup vs baseline: 1.8148x; 1.8148x over previous
//
#include <hip/hip_runtime.h>

constexpr int B = 8, N = 8192, S = 2048, D = 64, K = 16, C = 3 + D;
constexpr int G = 4;  // queries per wave

// Map float -> monotonically sortable unsigned (total order matches float <)
__device__ __forceinline__ unsigned sortable(float f) {
    unsigned u = __float_as_uint(f);
    unsigned mask = (unsigned)(((int)u) >> 31) | 0x80000000u;
    return u ^ mask;
}

// Wave-uniform load -> SGPR
__device__ __forceinline__ float uload(const float* p) {
    return __uint_as_float(__builtin_amdgcn_readfirstlane(__float_as_uint(*p)));
}

// Scalar reference-exact distance (fallback path): dot asc-FMA, d=(pn-2dot)+qn [R8]
__device__ __forceinline__ float make_d(float px, float py, float pz, float pnv,
                                        float qx, float qy, float qz, float qn) {
    float dot = __fmaf_rn(pz, qz, __fmaf_rn(py, qy, __fmul_rn(px, qx)));
    return __fadd_rn(__fsub_rn(pnv, __fmul_rn(2.0f, dot)), qn);
}

// v = pn - dot2 where dot2 = fma(pz,q2z, fma(py,q2y, px*q2x)) == 2*dot bitwise
__device__ __forceinline__ float make_v(float px, float py, float pz, float pnv,
                                        float q2x, float q2y, float q2z) {
    float dot2 = __fmaf_rn(pz, q2z, __fmaf_rn(py, q2y, __fmul_rn(px, q2x)));
    return __fsub_rn(pnv, dot2);
}

__device__ __forceinline__ float bitonic_sort64_f32(float v, int lane) {
#pragma unroll
    for (int k = 2; k <= 64; k <<= 1)
#pragma unroll
        for (int j = k >> 1; j > 0; j >>= 1) {
            float o = __shfl_xor(v, j, 64);
            bool keepmin = ((lane & k) == 0) == ((lane & j) == 0);
            float mn = fminf(v, o), mx = fmaxf(v, o);
            v = keepmin ? mn : mx;
        }
    return v;
}

__device__ __forceinline__ unsigned long long bitonic_sort64_u64(unsigned long long v, int lane) {
#pragma unroll
    for (int k = 2; k <= 64; k <<= 1)
#pragma unroll
        for (int j = k >> 1; j > 0; j >>= 1) {
            unsigned long long o = __shfl_xor(v, j, 64);
            bool keepmin = ((lane & k) == 0) == ((lane & j) == 0);
            v = ((v < o) == keepmin) ? v : o;
        }
    return v;
}

// pts4[b][n] = {x, y, z, ||p||^2}; norm = (z*z + y*y) + x*x desc no-FMA [verified R8]
__global__ void pack_kernel(const float* __restrict__ pts, float4* __restrict__ pts4) {
    int t = blockIdx.x * blockDim.x + threadIdx.x;
    if (t >= B * N) return;
    int b = t >> 13, n = t & (N - 1);
    const float* P = pts + (size_t)b * 3 * N;
    float x = P[n], y = P[N + n], z = P[2 * N + n];
    float pn = __fadd_rn(__fadd_rn(__fmul_rn(z, z), __fmul_rn(y, y)), __fmul_rn(x, x));
    pts4[t] = make_float4(x, y, z, pn);
}

// feat [B][D][N] -> featT [B][N][D], LDS-tiled 64x64
__global__ void __launch_bounds__(256) transpose_kernel(const float* __restrict__ feat,
                                                        float* __restrict__ featT) {
    __shared__ float tile[64][65];
    int b = blockIdx.x >> 7;
    int n0 = (blockIdx.x & 127) << 6;
    int col = threadIdx.x & 63;
    int crow = threadIdx.x >> 6;
    const float* F = feat + (size_t)b * D * N;
#pragma unroll
    for (int i = 0; i < 16; ++i) {
        int c = i * 4 + crow;
        tile[c][col] = F[(size_t)c * N + n0 + col];
    }
    __syncthreads();
    float* FT = featT + ((size_t)b * N + n0) * D;
#pragma unroll
    for (int i = 0; i < 16; ++i) {
        int nl = i * 4 + crow;
        FT[(size_t)nl * D + col] = tile[col][nl];
    }
}

// One wave per (query-group, candidate-half): scans N/2 candidates for G=4
// queries, two-pass threshold select (wave-private, R12-verified structure),
// emits the half's SORTED top-16 (d,idx) keys per query to half_out.
// Global top-16 of a query = 16 smallest of its two halves' top-16s (merge_kernel).
__global__ void __launch_bounds__(256) knn_half_kernel(const float4* __restrict__ pts4,
                                                       const float* __restrict__ newp,
                                                       unsigned long long* __restrict__ half_out) {
    __shared__ unsigned long long buf[4][G][64];
    __shared__ int cnt_lds[4][G];
    int wib = threadIdx.x >> 6;
    int lane = threadIdx.x & 63;
    int wid = blockIdx.x * 4 + wib;  // 0 .. B*S/G*2 - 1
    int qg = wid >> 1;               // query group
    int h = wid & 1;                 // candidate half
    int b = qg >> 9;                 // S/G = 512 groups per batch
    int sbase = (qg & 511) * G;
    const float4* P4 = pts4 + (size_t)b * N;
    const float* Q = newp + (size_t)b * 3 * S;
    if (lane < G) cnt_lds[wib][lane] = 0;
    float qn[G], q2x[G], q2y[G], q2z[G];
#pragma unroll
    for (int g = 0; g < G; ++g) {
        int s = sbase + g;
        float qx = uload(Q + s), qy = uload(Q + S + s), qz = uload(Q + 2 * S + s);
        qn[g] = __fadd_rn(__fadd_rn(__fmul_rn(qz, qz), __fmul_rn(qy, qy)), __fmul_rn(qx, qx));
        q2x[g] = 2.0f * qx;  // exact pow-2 scale
        q2y[g] = 2.0f * qy;
        q2z[g] = 2.0f * qz;
    }
    int chunk0 = h * (N / 2);

    // ---- pass 1: per-lane min of v over this half ----
    float m[G];
#pragma unroll
    for (int g = 0; g < G; ++g) m[g] = __int_as_float(0x7f800000);
    for (int blk = 0; blk < N / 2 / 256; ++blk) {
        int nb = chunk0 + blk * 256 + lane;
        float4 c0 = P4[nb], c1 = P4[nb + 64], c2 = P4[nb + 128], c3 = P4[nb + 192];
#pragma unroll
        for (int g = 0; g < G; ++g) {
            float v0 = make_v(c0.x, c0.y, c0.z, c0.w, q2x[g], q2y[g], q2z[g]);
            float v1 = make_v(c1.x, c1.y, c1.z, c1.w, q2x[g], q2y[g], q2z[g]);
            float v2 = make_v(c2.x, c2.y, c2.z, c2.w, q2x[g], q2y[g], q2z[g]);
            float v3 = make_v(c3.x, c3.y, c3.z, c3.w, q2x[g], q2y[g], q2z[g]);
            m[g] = fminf(m[g], fminf(fminf(v0, v1), fminf(v2, v3)));
        }
    }
    float tau_d[G], vthr[G];
#pragma unroll
    for (int g = 0; g < G; ++g) {
        float tau_v = __shfl(bitonic_sort64_f32(m[g], lane), 15, 64);  // >= half's 16th v
        tau_d[g] = __fadd_rn(tau_v, qn[g]);  // valid upper bound on half's 16th distance
        vthr[g] = __fadd_rn(__fsub_rn(tau_d[g], qn[g]), 1e-4f);  // superset pre-filter
    }

    // ---- pass 2: pre-filter on v, exact d check + wave LDS-atomic compact ----
    for (int blk = 0; blk < N / 2 / 256; ++blk) {
        int nb = chunk0 + blk * 256 + lane;
        float4 c0 = P4[nb], c1 = P4[nb + 64], c2 = P4[nb + 128], c3 = P4[nb + 192];
#pragma unroll
        for (int g = 0; g < G; ++g) {
            float vv[4];
            vv[0] = make_v(c0.x, c0.y, c0.z, c0.w, q2x[g], q2y[g], q2z[g]);
            vv[1] = make_v(c1.x, c1.y, c1.z, c1.w, q2x[g], q2y[g], q2z[g]);
            vv[2] = make_v(c2.x, c2.y, c2.z, c2.w, q2x[g], q2y[g], q2z[g]);
            vv[3] = make_v(c3.x, c3.y, c3.z, c3.w, q2x[g], q2y[g], q2z[g]);
#pragma unroll
            for (int i = 0; i < 4; ++i) {
                if (vv[i] <= vthr[g]) {  // rare divergent branch
                    float d = __fadd_rn(vv[i], qn[g]);  // exact reference d
                    if (d <= tau_d[g]) {
                        int pos = atomicAdd(&cnt_lds[wib][g], 1);
                        if (pos < 64)
                            buf[wib][g][pos] =
                                ((unsigned long long)sortable(d) << 32) | (unsigned)(nb + i * 64);
                    }
                }
            }
        }
    }
    __syncthreads();

#pragma unroll
    for (int g = 0; g < G; ++g) {
        int cnt = cnt_lds[wib][g];
        unsigned long long* ho = half_out + (((size_t)(qg * G + g)) * 2 + h) * K;
        if (cnt <= 64) {
            unsigned long long key = (lane < cnt) ? buf[wib][g][lane] : ~0ull;
            key = bitonic_sort64_u64(key, lane);
            if (lane < K) ho[lane] = key;  // sorted half-top-16
        } else {
            // Exact fallback (never expected): rescan this half, per-lane top-16 + merge.
            float qx = 0.5f * q2x[g], qy = 0.5f * q2y[g], qz = 0.5f * q2z[g];
            unsigned long long a[K];
#pragma unroll
            for (int i = 0; i < K; ++i) a[i] = ~0ull;
            for (int n = chunk0 + lane; n < chunk0 + N / 2; n += 64) {
                float4 c = P4[n];
                float d = make_d(c.x, c.y, c.z, c.w, qx, qy, qz, qn[g]);
                unsigned long long key = ((unsigned long long)sortable(d) << 32) | (unsigned)n;
                if (key < a[K - 1]) {
#pragma unroll
                    for (int i = K - 1; i >= 1; --i) {
                        unsigned long long lo = a[i - 1];
                        a[i] = key < lo ? lo : (key < a[i] ? key : a[i]);
                    }
                    a[0] = key < a[0] ? key : a[0];
                }
            }
            for (int r = 0; r < K; ++r) {
                unsigned long long best = a[0];
#pragma unroll
                for (int mm = 1; mm < 64; mm <<= 1) {
                    unsigned long long o = __shfl_xor(best, mm, 64);
                    best = o < best ? o : best;
                }
                if (lane == 0) ho[r] = best;
                bool won = (a[0] == best);
#pragma unroll
                for (int i = 0; i < K - 1; ++i) a[i] = won ? a[i + 1] : a[i];
                a[K - 1] = won ? ~0ull : a[K - 1];
            }
        }
    }
}

// Merge two sorted 16-lists per query (bitonic merge, 5 shuffle stages), emit 16 inds.
__global__ void __launch_bounds__(256) merge_kernel(const unsigned long long* __restrict__ half_out,
                                                    int* __restrict__ ind) {
    int wib = threadIdx.x >> 6;
    int lane = threadIdx.x & 63;
    int qid = blockIdx.x * 4 + wib;  // 0 .. B*S-1
    const unsigned long long* Hq = half_out + (size_t)qid * 2 * K;
    unsigned long long k = ~0ull;
    if (lane < 16) k = Hq[lane];                 // half 0 ascending
    else if (lane < 32) k = Hq[16 + (31 - lane)];  // half 1 descending -> bitonic
#pragma unroll
    for (int j = 16; j > 0; j >>= 1) {
        unsigned long long o = __shfl_xor(k, j, 64);
        bool keepmin = (lane & j) == 0;
        k = ((k < o) == keepmin) ? k : o;
    }
    if (lane < K) ind[(size_t)qid * K + lane] = (int)(unsigned)k;
}

// Output [B][C][K][S]. t -> (b, g, k, s); g=0: 3 coord channels from pts4;
// g=1..16: 4 feat channels via one float4 from featT (or 4 scalar loads).
__global__ void __launch_bounds__(256) gather_kernel(const float4* __restrict__ pts4,
                                                     const float* __restrict__ newp,
                                                     const float* __restrict__ feat,
                                                     const float* __restrict__ featT,
                                                     const int* __restrict__ ind,
                                                     float* __restrict__ out, int useT) {
    int t = blockIdx.x * blockDim.x + threadIdx.x;
    int s = t & (S - 1);
    int k = (t >> 11) & (K - 1);
    int rest = t >> 15;
    int g = rest % 17;
    int b = rest / 17;
    if (b >= B) return;
    int id = ind[((size_t)b * S + s) * K + k];
    size_t KS = (size_t)K * S;
    if (g == 0) {
        float4 p = pts4[(size_t)b * N + id];
        const float* Q = newp + (size_t)b * 3 * S;
        float* o = out + ((size_t)b * C * K + k) * S + s;
        o[0] = __fsub_rn(p.x, Q[s]);
        o[KS] = __fsub_rn(p.y, Q[S + s]);
        o[2 * KS] = __fsub_rn(p.z, Q[2 * S + s]);
    } else {
        int cb = (g - 1) * 4;
        float4 f;
        if (useT) {
            f = *(const float4*)(featT + ((size_t)b * N + id) * D + cb);
        } else {
            const float* F = feat + (size_t)b * D * N;
            f = make_float4(F[(size_t)cb * N + id], F[(size_t)(cb + 1) * N + id],
                            F[(size_t)(cb + 2) * N + id], F[(size_t)(cb + 3) * N + id]);
        }
        float* o = out + (((size_t)b * C + 3 + cb) * K + k) * S + s;
        o[0] = f.x;
        o[KS] = f.y;
        o[2 * KS] = f.z;
        o[3 * KS] = f.w;
    }
}

extern "C" void kernel_launch(void* const* d_in, const int* in_sizes, int n_in,
                              void* d_out, int out_size, void* d_ws, size_t ws_size,
                              hipStream_t stream) {
    const float* pts = (const float*)d_in[0];   // [B, 3, N]
    const float* newp = (const float*)d_in[1];  // [B, 3, S]
    const float* feat = (const float*)d_in[2];  // [B, D, N]
    float* out = (float*)d_out;                 // [B, C, K, S]

    size_t off_ind = 0;
    size_t off_half = (size_t)B * S * K * sizeof(int);                            // 2 MB
    size_t off_pts4 = off_half + (size_t)B * S * 2 * K * sizeof(unsigned long long);  // +4 MB
    size_t off_featT = off_pts4 + (size_t)B * N * sizeof(float4);                 // +1 MB
    size_t need = off_featT + (size_t)B * N * D * sizeof(float);                  // +16 MB
    int* ind = (int*)((char*)d_ws + off_ind);
    unsigned long long* half_out = (unsigned long long*)((char*)d_ws + off_half);
    float4* pts4 = (float4*)((char*)d_ws + off_pts4);
    float* featT = (float*)((char*)d_ws + off_featT);
    int useT = (ws_size >= need) ? 1 : 0;

    pack_kernel<<<(B * N) / 256, 256, 0, stream>>>(pts, pts4);
    if (useT) transpose_kernel<<<B * (N / 64), 256, 0, stream>>>(feat, featT);
    knn_half_kernel<<<(B * S / G * 2) / 4, 256, 0, stream>>>(pts4, newp, half_out);
    merge_kernel<<<(B * S) / 4, 256, 0, stream>>>(half_out, ind);
    gather_kernel<<<(B * 17 * K * S) / 256, 256, 0, stream>>>(pts4, newp, feat, featT, ind, out, useT);
}

// Round 15
// 116.457 us; speedup vs baseline: 2.0550x; 1.1323x over previous
//
#include <hip/hip_runtime.h>

constexpr int B = 8, N = 8192, S = 2048, D = 64, K = 16, C = 3 + D;
constexpr int G = 4;  // queries per wave

// Map float -> monotonically sortable unsigned (total order matches float <)
__device__ __forceinline__ unsigned sortable(float f) {
    unsigned u = __float_as_uint(f);
    unsigned mask = (unsigned)(((int)u) >> 31) | 0x80000000u;
    return u ^ mask;
}

// Wave-uniform load -> SGPR
__device__ __forceinline__ float uload(const float* p) {
    return __uint_as_float(__builtin_amdgcn_readfirstlane(__float_as_uint(*p)));
}

// Scalar reference-exact distance (fallback path): dot asc-FMA, d=(pn-2dot)+qn [R8]
__device__ __forceinline__ float make_d(float px, float py, float pz, float pnv,
                                        float qx, float qy, float qz, float qn) {
    float dot = __fmaf_rn(pz, qz, __fmaf_rn(py, qy, __fmul_rn(px, qx)));
    return __fadd_rn(__fsub_rn(pnv, __fmul_rn(2.0f, dot)), qn);
}

// EXACT v = pn - dot2; dot2 = fma(pz,q2z, fma(py,q2y, px*q2x)) == 2*dot bitwise
__device__ __forceinline__ float make_v(float px, float py, float pz, float pnv,
                                        float q2x, float q2y, float q2z) {
    float dot2 = __fmaf_rn(pz, q2z, __fmaf_rn(py, q2y, __fmul_rn(px, q2x)));
    return __fsub_rn(pnv, dot2);
}

// FUSED 3-FMA proxy: |vt - exact v| <= ~3e-5; used only with >= 1e-4 margins
__device__ __forceinline__ float make_vt(float px, float py, float pz, float pnv,
                                         float nq2x, float nq2y, float nq2z) {
    return __fmaf_rn(px, nq2x, __fmaf_rn(py, nq2y, __fmaf_rn(pz, nq2z, pnv)));
}

__device__ __forceinline__ float bitonic_sort64_f32(float v, int lane) {
#pragma unroll
    for (int k = 2; k <= 64; k <<= 1)
#pragma unroll
        for (int j = k >> 1; j > 0; j >>= 1) {
            float o = __shfl_xor(v, j, 64);
            bool keepmin = ((lane & k) == 0) == ((lane & j) == 0);
            float mn = fminf(v, o), mx = fmaxf(v, o);
            v = keepmin ? mn : mx;
        }
    return v;
}

__device__ __forceinline__ unsigned long long bitonic_sort64_u64(unsigned long long v, int lane) {
#pragma unroll
    for (int k = 2; k <= 64; k <<= 1)
#pragma unroll
        for (int j = k >> 1; j > 0; j >>= 1) {
            unsigned long long o = __shfl_xor(v, j, 64);
            bool keepmin = ((lane & k) == 0) == ((lane & j) == 0);
            v = ((v < o) == keepmin) ? v : o;
        }
    return v;
}

// pts4[b][n] = {x, y, z, ||p||^2}; norm = (z*z + y*y) + x*x desc no-FMA [verified R8]
__global__ void pack_kernel(const float* __restrict__ pts, float4* __restrict__ pts4) {
    int t = blockIdx.x * blockDim.x + threadIdx.x;
    if (t >= B * N) return;
    int b = t >> 13, n = t & (N - 1);
    const float* P = pts + (size_t)b * 3 * N;
    float x = P[n], y = P[N + n], z = P[2 * N + n];
    float pn = __fadd_rn(__fadd_rn(__fmul_rn(z, z), __fmul_rn(y, y)), __fmul_rn(x, x));
    pts4[t] = make_float4(x, y, z, pn);
}

// feat [B][D][N] -> featT [B][N][D], LDS-tiled 64x64
__global__ void __launch_bounds__(256) transpose_kernel(const float* __restrict__ feat,
                                                        float* __restrict__ featT) {
    __shared__ float tile[64][65];
    int b = blockIdx.x >> 7;
    int n0 = (blockIdx.x & 127) << 6;
    int col = threadIdx.x & 63;
    int crow = threadIdx.x >> 6;
    const float* F = feat + (size_t)b * D * N;
#pragma unroll
    for (int i = 0; i < 16; ++i) {
        int c = i * 4 + crow;
        tile[c][col] = F[(size_t)c * N + n0 + col];
    }
    __syncthreads();
    float* FT = featT + ((size_t)b * N + n0) * D;
#pragma unroll
    for (int i = 0; i < 16; ++i) {
        int nl = i * 4 + crow;
        FT[(size_t)nl * D + col] = tile[col][nl];
    }
}

// One wave per G=4 queries, two-pass threshold selection (R12 structure).
// Pass 1: per-lane min of FUSED vt; tau_d = rn(tau_vt + qn) + 1e-4 is a valid
// upper bound on the 16th distance (witnesses: 16 lanes with vt-min <= tau_vt,
// their exact d <= tau_d by the 3e-5 proxy bound + margin). Pass 2: prefilter
// vt <= vthr (superset, margin covers proxy error), hits recompute EXACT v,d
// and check d <= tau_d; LDS-atomic compact; exact (d,idx) u64 bitonic sort.
__global__ void __launch_bounds__(256) knn_kernel(const float4* __restrict__ pts4,
                                                  const float* __restrict__ newp,
                                                  int* __restrict__ ind) {
    __shared__ unsigned long long buf[4][G][64];
    __shared__ int cnt_lds[4][G];
    int wib = threadIdx.x >> 6;
    int lane = threadIdx.x & 63;
    int wid = blockIdx.x * 4 + wib;
    int b = wid >> 9;
    int sbase = (wid & 511) * G;
    const float4* P4 = pts4 + (size_t)b * N;
    const float* Q = newp + (size_t)b * 3 * S;
    if (lane < G) cnt_lds[wib][lane] = 0;
    float qn[G], q2x[G], q2y[G], q2z[G], nq2x[G], nq2y[G], nq2z[G];
#pragma unroll
    for (int g = 0; g < G; ++g) {
        int s = sbase + g;
        float qx = uload(Q + s), qy = uload(Q + S + s), qz = uload(Q + 2 * S + s);
        qn[g] = __fadd_rn(__fadd_rn(__fmul_rn(qz, qz), __fmul_rn(qy, qy)), __fmul_rn(qx, qx));
        q2x[g] = 2.0f * qx;  // exact pow-2 scale
        q2y[g] = 2.0f * qy;
        q2z[g] = 2.0f * qz;
        nq2x[g] = -q2x[g];
        nq2y[g] = -q2y[g];
        nq2z[g] = -q2z[g];
    }

    // ---- pass 1: per-lane min of fused vt over 128 candidates ----
    float m[G];
#pragma unroll
    for (int g = 0; g < G; ++g) m[g] = __int_as_float(0x7f800000);
#pragma unroll 2
    for (int blk = 0; blk < N / 256; ++blk) {
        int nb = blk * 256 + lane;
        float4 c0 = P4[nb], c1 = P4[nb + 64], c2 = P4[nb + 128], c3 = P4[nb + 192];
#pragma unroll
        for (int g = 0; g < G; ++g) {
            float v0 = make_vt(c0.x, c0.y, c0.z, c0.w, nq2x[g], nq2y[g], nq2z[g]);
            float v1 = make_vt(c1.x, c1.y, c1.z, c1.w, nq2x[g], nq2y[g], nq2z[g]);
            float v2 = make_vt(c2.x, c2.y, c2.z, c2.w, nq2x[g], nq2y[g], nq2z[g]);
            float v3 = make_vt(c3.x, c3.y, c3.z, c3.w, nq2x[g], nq2y[g], nq2z[g]);
            m[g] = fminf(m[g], fminf(fminf(v0, v1), fminf(v2, v3)));
        }
    }
    float tau_d[G], vthr[G];
#pragma unroll
    for (int g = 0; g < G; ++g) {
        float tau_vt = __shfl(bitonic_sort64_f32(m[g], lane), 15, 64);
        tau_d[g] = __fadd_rn(__fadd_rn(tau_vt, qn[g]), 1e-4f);  // >= 16th distance
        vthr[g] = __fadd_rn(__fsub_rn(tau_d[g], qn[g]), 1e-4f); // superset prefilter on vt
    }

    // ---- pass 2: prefilter on fused vt; hits do exact v,d + atomic compact ----
    for (int blk = 0; blk < N / 256; ++blk) {
        int nb = blk * 256 + lane;
        float4 cc[4] = {P4[nb], P4[nb + 64], P4[nb + 128], P4[nb + 192]};
#pragma unroll
        for (int g = 0; g < G; ++g) {
#pragma unroll
            for (int i = 0; i < 4; ++i) {
                float vt = make_vt(cc[i].x, cc[i].y, cc[i].z, cc[i].w, nq2x[g], nq2y[g], nq2z[g]);
                if (vt <= vthr[g]) {  // rare divergent branch
                    // exact reference arithmetic on the hit
                    float v = make_v(cc[i].x, cc[i].y, cc[i].z, cc[i].w, q2x[g], q2y[g], q2z[g]);
                    float d = __fadd_rn(v, qn[g]);
                    if (d <= tau_d[g]) {
                        int pos = atomicAdd(&cnt_lds[wib][g], 1);
                        if (pos < 64)
                            buf[wib][g][pos] =
                                ((unsigned long long)sortable(d) << 32) | (unsigned)(nb + i * 64);
                    }
                }
            }
        }
    }
    __syncthreads();

#pragma unroll
    for (int g = 0; g < G; ++g) {
        int cnt = cnt_lds[wib][g];
        int* my_ind = ind + ((size_t)b * S + sbase + g) * K;
        if (cnt <= 64) {
            unsigned long long key = (lane < cnt) ? buf[wib][g][lane] : ~0ull;
            key = bitonic_sort64_u64(key, lane);
            if (lane < K) my_ind[lane] = (int)(unsigned)key;
        } else {
            // Exact fallback (never expected on random data)
            float qx = 0.5f * q2x[g], qy = 0.5f * q2y[g], qz = 0.5f * q2z[g];
            unsigned long long a[K];
#pragma unroll
            for (int i = 0; i < K; ++i) a[i] = ~0ull;
            for (int n = lane; n < N; n += 64) {
                float4 c = P4[n];
                float d = make_d(c.x, c.y, c.z, c.w, qx, qy, qz, qn[g]);
                unsigned long long key = ((unsigned long long)sortable(d) << 32) | (unsigned)n;
                if (key < a[K - 1]) {
#pragma unroll
                    for (int i = K - 1; i >= 1; --i) {
                        unsigned long long lo = a[i - 1];
                        a[i] = key < lo ? lo : (key < a[i] ? key : a[i]);
                    }
                    a[0] = key < a[0] ? key : a[0];
                }
            }
            for (int r = 0; r < K; ++r) {
                unsigned long long best = a[0];
#pragma unroll
                for (int mm = 1; mm < 64; mm <<= 1) {
                    unsigned long long o = __shfl_xor(best, mm, 64);
                    best = o < best ? o : best;
                }
                if (lane == 0) my_ind[r] = (int)(unsigned)best;
                bool won = (a[0] == best);
#pragma unroll
                for (int i = 0; i < K - 1; ++i) a[i] = won ? a[i + 1] : a[i];
                a[K - 1] = won ? ~0ull : a[K - 1];
            }
        }
    }
}

// Output [B][C][K][S]. t -> (b, g, k, s); g=0: 3 coord channels from pts4;
// g=1..16: 4 feat channels via one float4 from featT (or 4 scalar loads).
__global__ void __launch_bounds__(256) gather_kernel(const float4* __restrict__ pts4,
                                                     const float* __restrict__ newp,
                                                     const float* __restrict__ feat,
                                                     const float* __restrict__ featT,
                                                     const int* __restrict__ ind,
                                                     float* __restrict__ out, int useT) {
    int t = blockIdx.x * blockDim.x + threadIdx.x;
    int s = t & (S - 1);
    int k = (t >> 11) & (K - 1);
    int rest = t >> 15;
    int g = rest % 17;
    int b = rest / 17;
    if (b >= B) return;
    int id = ind[((size_t)b * S + s) * K + k];
    size_t KS = (size_t)K * S;
    if (g == 0) {
        float4 p = pts4[(size_t)b * N + id];
        const float* Q = newp + (size_t)b * 3 * S;
        float* o = out + ((size_t)b * C * K + k) * S + s;
        o[0] = __fsub_rn(p.x, Q[s]);
        o[KS] = __fsub_rn(p.y, Q[S + s]);
        o[2 * KS] = __fsub_rn(p.z, Q[2 * S + s]);
    } else {
        int cb = (g - 1) * 4;
        float4 f;
        if (useT) {
            f = *(const float4*)(featT + ((size_t)b * N + id) * D + cb);
        } else {
            const float* F = feat + (size_t)b * D * N;
            f = make_float4(F[(size_t)cb * N + id], F[(size_t)(cb + 1) * N + id],
                            F[(size_t)(cb + 2) * N + id], F[(size_t)(cb + 3) * N + id]);
        }
        float* o = out + (((size_t)b * C + 3 + cb) * K + k) * S + s;
        o[0] = f.x;
        o[KS] = f.y;
        o[2 * KS] = f.z;
        o[3 * KS] = f.w;
    }
}

extern "C" void kernel_launch(void* const* d_in, const int* in_sizes, int n_in,
                              void* d_out, int out_size, void* d_ws, size_t ws_size,
                              hipStream_t stream) {
    const float* pts = (const float*)d_in[0];   // [B, 3, N]
    const float* newp = (const float*)d_in[1];  // [B, 3, S]
    const float* feat = (const float*)d_in[2];  // [B, D, N]
    float* out = (float*)d_out;                 // [B, C, K, S]

    size_t off_ind = 0;
    size_t off_pts4 = (size_t)B * S * K * sizeof(int);              // 2 MB
    size_t off_featT = off_pts4 + (size_t)B * N * sizeof(float4);   // +1 MB
    size_t need = off_featT + (size_t)B * N * D * sizeof(float);    // +16 MB
    int* ind = (int*)((char*)d_ws + off_ind);
    float4* pts4 = (float4*)((char*)d_ws + off_pts4);
    float* featT = (float*)((char*)d_ws + off_featT);
    int useT = (ws_size >= need) ? 1 : 0;

    pack_kernel<<<(B * N) / 256, 256, 0, stream>>>(pts, pts4);
    if (useT) transpose_kernel<<<B * (N / 64), 256, 0, stream>>>(feat, featT);
    knn_kernel<<<(B * S) / (G * 4), 256, 0, stream>>>(pts4, newp, ind);
    gather_kernel<<<(B * 17 * K * S) / 256, 256, 0, stream>>>(pts4, newp, feat, featT, ind, out, useT);
}